// Round 1
// baseline (315.166 us; speedup 1.0000x reference)
//
#include <hip/hip_runtime.h>
#include <hip/hip_cooperative_groups.h>
#include <math.h>

namespace cg = cooperative_groups;

// Model_7310034338114: two Flaubert/XLM MHA blocks (eval), fp32 in/out.
// inst0: x (4,1024,192), 16 heads, dph=12. inst1: y (4,1024,66), 11 heads, dph=6.
//
// Round 12: single persistent cooperative kernel. r11's four kernels
// (compact -> qkv -> attn -> oproj) are each <42us but sum to 156us: the
// roofline says ~6us of HBM traffic and ~2us of MFMA work, so the time is
// launch/drain serialization + low-occupancy tails (oproj: 320 blocks =
// 1.25/CU). Fusion: grid = 1024 blocks (4/CU co-resident, LDS 36.9KB =
// oproj's need), phases separated by grid.sync(). Phase internals are
// byte-identical to r11. Fallback to the proven 4-kernel path if the
// cooperative launch is rejected.

#define BS 4
#define SLEN 1024

// workspace float offsets
#define Q0_OFF 0              // f32 [4][16][1024][12]  (786432)
#define C0_OFF 786432         // f32 [4096][192]        (786432)
#define Q1_OFF 1572864        // f32 [4][11][1024][6]   (270336)
#define C1_OFF 1843200        // f32 [4096][66]         (270336)
#define K0H_OFF 2113536       // f16 [4][16][1024][12]  (786432 h = 393216 fl)
#define V0T_OFF 2506752       // f16 [4][16][12][1024]  (786432 h)
#define K1H_OFF 2899968       // f16 [4][11][1024][8]   (360448 h = 180224 fl)
#define V1T_OFF 3080192       // f16 [4][11][6][1024]   (270336 h = 135168 fl)
#define CMAP0_OFF 3215360     // int [4][1024]
#define CMAP1_OFF 3219456     // int [4][1024]
#define CNT_OFF 3223552       // int [8] (inst*4 + b)

#define OUT0_SIZE 786432      // 4096*192

#define FUSED_SMEM 36864      // oproj needs 4*64*72*2; attn 12800; qkv 18432

#if __has_builtin(__builtin_amdgcn_exp2f)
#define EXP2(x) __builtin_amdgcn_exp2f(x)
#else
#define EXP2(x) __expf((x) * 0.69314718056f)
#endif

typedef _Float16 f16x2 __attribute__((ext_vector_type(2)));
typedef _Float16 f16x4 __attribute__((ext_vector_type(4)));
typedef _Float16 f16x8 __attribute__((ext_vector_type(8)));
typedef float f32x4 __attribute__((ext_vector_type(4)));

union F16x8U { f16x8 v8; f16x4 v4[2]; };

// ---------------------------------------------------------------------------
// Key compaction: per (inst, b), cmap[s] = dest slot (unmasked first, stable),
// cnts = number of unmasked keys. 256 threads, 4 keys/thread.
// ---------------------------------------------------------------------------
__device__ void compact_phase(int item, const int* __restrict__ mask0,
                              const int* __restrict__ mask1,
                              int* __restrict__ cmap0, int* __restrict__ cmap1,
                              int* __restrict__ cnts, int* sS, int* sTot)
{
  const int inst = item >> 2, b = item & 3;
  const int* m = (inst ? mask1 : mask0) + b * SLEN;
  int* cmap = (inst ? cmap1 : cmap0) + b * SLEN;
  const int tid = threadIdx.x;

  int mv[4], s4 = 0;
#pragma unroll
  for (int i = 0; i < 4; ++i) { mv[i] = m[tid * 4 + i] ? 1 : 0; s4 += mv[i]; }
  sS[tid] = s4;
  __syncthreads();
  for (int off = 1; off < 256; off <<= 1) {   // Hillis-Steele inclusive scan
    const int v = sS[tid];
    const int add = (tid >= off) ? sS[tid - off] : 0;
    __syncthreads();
    sS[tid] = v + add;
    __syncthreads();
  }
  if (tid == 255) *sTot = sS[255];
  __syncthreads();
  const int tot = *sTot;
  int u = tid ? sS[tid - 1] : 0;   // unmasked count before this thread's span
#pragma unroll
  for (int i = 0; i < 4; ++i) {
    const int s = tid * 4 + i;
    cmap[s] = mv[i] ? u : tot + (s - u);
    u += mv[i];
  }
  if (tid == 0) cnts[item] = tot;
  __syncthreads();   // LDS safely reusable after return
}

__global__ __launch_bounds__(256) void compact_kernel(
    const int* __restrict__ mask0, const int* __restrict__ mask1,
    int* __restrict__ cmap0, int* __restrict__ cmap1, int* __restrict__ cnts)
{
  __shared__ int sS[256];
  __shared__ int sTot;
  compact_phase(blockIdx.x, mask0, mask1, cmap0, cmap1, cnts, sS, &sTot);
}

// ---------------------------------------------------------------------------
// f16-MFMA GEMM building blocks (round-4 proven): BM=BN=BK=64, 4 waves.
// ---------------------------------------------------------------------------
__device__ __forceinline__ void mfma_chunk(const _Float16* sA, const _Float16* sWT,
                                           int wv, int lane, f32x4 acc[4])
{
  const int col = lane & 15, grp = lane >> 4;
#pragma unroll
  for (int ks = 0; ks < 2; ++ks) {
    const f16x8 bf = *(const f16x8*)(sWT + (wv * 16 + col) * 72 + ks * 32 + grp * 8);
#pragma unroll
    for (int mt = 0; mt < 4; ++mt) {
      const f16x8 af = *(const f16x8*)(sA + (mt * 16 + col) * 72 + ks * 32 + grp * 8);
      acc[mt] = __builtin_amdgcn_mfma_f32_16x16x32_f16(af, bf, acc[mt], 0, 0, 0);
    }
  }
}

__device__ __forceinline__ void mfma_chunk_split(
    const _Float16* sAh, const _Float16* sAl,
    const _Float16* sWTh, const _Float16* sWTl,
    int wv, int lane, f32x4 acc[4])
{
  const int col = lane & 15, grp = lane >> 4;
#pragma unroll
  for (int ks = 0; ks < 2; ++ks) {
    const int boff = (wv * 16 + col) * 72 + ks * 32 + grp * 8;
    const f16x8 bh = *(const f16x8*)(sWTh + boff);
    const f16x8 bl = *(const f16x8*)(sWTl + boff);
#pragma unroll
    for (int mt = 0; mt < 4; ++mt) {
      const int aoff = (mt * 16 + col) * 72 + ks * 32 + grp * 8;
      const f16x8 ah = *(const f16x8*)(sAh + aoff);
      const f16x8 al = *(const f16x8*)(sAl + aoff);
      acc[mt] = __builtin_amdgcn_mfma_f32_16x16x32_f16(ah, bh, acc[mt], 0, 0, 0);
      acc[mt] = __builtin_amdgcn_mfma_f32_16x16x32_f16(ah, bl, acc[mt], 0, 0, 0);
      acc[mt] = __builtin_amdgcn_mfma_f32_16x16x32_f16(al, bh, acc[mt], 0, 0, 0);
    }
  }
}

template <int DIM>
__device__ __forceinline__ void stage_chunk(const float* __restrict__ A, int row0,
                                            int kc, const float* __restrict__ W,
                                            int col0, _Float16* sA, _Float16* sWT,
                                            int tid)
{
  for (int idx = tid; idx < 2048; idx += 256) {
    const int m = idx >> 5, k = (idx & 31) * 2;
    float2 v = make_float2(0.f, 0.f);
    if (kc + k < DIM) v = *(const float2*)(A + (size_t)(row0 + m) * DIM + kc + k);
    *(f16x2*)(sA + m * 72 + k) = (f16x2){(_Float16)v.x, (_Float16)v.y};
  }
  for (int idx = tid; idx < 2048; idx += 256) {
    const int k = idx >> 5, n = (idx & 31) * 2;
    float2 v = make_float2(0.f, 0.f);
    if (kc + k < DIM && col0 + n < DIM)
      v = *(const float2*)(W + (size_t)(kc + k) * DIM + col0 + n);
    sWT[n * 72 + k] = (_Float16)v.x;
    sWT[(n + 1) * 72 + k] = (_Float16)v.y;
  }
}

template <int DIM>
__device__ __forceinline__ void stage_chunk_split(
    const float* __restrict__ A, int row0, int kc,
    const float* __restrict__ W, int col0,
    _Float16* sAh, _Float16* sAl, _Float16* sWTh, _Float16* sWTl, int tid)
{
  for (int idx = tid; idx < 2048; idx += 256) {
    const int m = idx >> 5, k = (idx & 31) * 2;
    float2 v = make_float2(0.f, 0.f);
    if (kc + k < DIM) v = *(const float2*)(A + (size_t)(row0 + m) * DIM + kc + k);
    const _Float16 hx = (_Float16)v.x, hy = (_Float16)v.y;
    *(f16x2*)(sAh + m * 72 + k) = (f16x2){hx, hy};
    *(f16x2*)(sAl + m * 72 + k) =
        (f16x2){(_Float16)(v.x - (float)hx), (_Float16)(v.y - (float)hy)};
  }
  for (int idx = tid; idx < 2048; idx += 256) {
    const int k = idx >> 5, n = (idx & 31) * 2;
    float2 v = make_float2(0.f, 0.f);
    if (kc + k < DIM && col0 + n < DIM)
      v = *(const float2*)(W + (size_t)(kc + k) * DIM + col0 + n);
    const _Float16 hx = (_Float16)v.x, hy = (_Float16)v.y;
    sWTh[n * 72 + k] = hx;
    sWTh[(n + 1) * 72 + k] = hy;
    sWTl[n * 72 + k] = (_Float16)(v.x - (float)hx);
    sWTl[(n + 1) * 72 + k] = (_Float16)(v.y - (float)hy);
  }
}

// ---------------------------------------------------------------------------
// QKV projection: Q -> f32 [b][h][s][dph] scaled log2(e)/sqrt(dph);
// K -> f16 [b][h][cmap(s)][KST]; V -> f16 transposed [b][h][d][cmap(s)].
// ---------------------------------------------------------------------------
template <int DIM, int H, int DPH, int NT, int NCH, int KST>
__device__ void qkv_impl(int bid, const float* __restrict__ X,
                         const float* __restrict__ qw, const float* __restrict__ qb,
                         const float* __restrict__ kw, const float* __restrict__ kb,
                         const float* __restrict__ vw, const float* __restrict__ vb,
                         float* __restrict__ qo, _Float16* __restrict__ kh,
                         _Float16* __restrict__ vth, const int* __restrict__ cmap,
                         char* smem)
{
  const int mt64 = bid & 63;
  const int rest = bid >> 6;
  const int mat = rest / NT;
  const int nt = rest % NT;
  const int row0 = mt64 * 64, col0 = nt * 64;

  const float* W = (mat == 0) ? qw : (mat == 1) ? kw : vw;
  const float* B = (mat == 0) ? qb : (mat == 1) ? kb : vb;
  const float scale = (mat == 0) ? (1.44269504089f / sqrtf((float)DPH)) : 1.0f;

  _Float16* sA = (_Float16*)smem;
  _Float16* sWT = sA + 64 * 72;

  const int tid = threadIdx.x;
  const int wv = tid >> 6, lane = tid & 63;
  f32x4 acc[4] = {{0.f,0.f,0.f,0.f},{0.f,0.f,0.f,0.f},{0.f,0.f,0.f,0.f},{0.f,0.f,0.f,0.f}};

  for (int c = 0; c < NCH; ++c) {
    __syncthreads();
    stage_chunk<DIM>(X, row0, c * 64, W, col0, sA, sWT, tid);
    __syncthreads();
    mfma_chunk(sA, sWT, wv, lane, acc);
  }

  const int col = lane & 15, grp = lane >> 4;
  const int cidx = col0 + wv * 16 + col;
  if (cidx < DIM) {
    const float bias = B[cidx];
    const int h = cidx / DPH, d = cidx % DPH;
#pragma unroll
    for (int mt = 0; mt < 4; ++mt) {
#pragma unroll
      for (int r = 0; r < 4; ++r) {
        const int m = row0 + mt * 16 + grp * 4 + r;
        const int b = m >> 10, s = m & 1023;
        const float v = acc[mt][r] + bias;
        const int bh = b * H + h;
        if (mat == 0) {
          qo[(size_t)((bh << 10) + s) * DPH + d] = v * scale;
        } else {
          const int sp = cmap[(b << 10) + s];
          if (mat == 1)
            kh[(size_t)((bh << 10) + sp) * KST + d] = (_Float16)v;
          else
            vth[((size_t)(bh * DPH + d) << 10) + sp] = (_Float16)v;
        }
      }
    }
  }
}

__global__ __launch_bounds__(256) void qkv_kernel(
    const float* __restrict__ x, const float* __restrict__ y,
    const float* __restrict__ q0w, const float* __restrict__ q0b,
    const float* __restrict__ k0w, const float* __restrict__ k0b,
    const float* __restrict__ v0w, const float* __restrict__ v0b,
    const float* __restrict__ q1w, const float* __restrict__ q1b,
    const float* __restrict__ k1w, const float* __restrict__ k1b,
    const float* __restrict__ v1w, const float* __restrict__ v1b,
    float* __restrict__ ws)
{
  extern __shared__ char smem[];
  _Float16* hws = (_Float16*)ws;
  const int* cmap0 = (const int*)(ws + CMAP0_OFF);
  const int* cmap1 = (const int*)(ws + CMAP1_OFF);
  const int bid = blockIdx.x;
  if (bid < 576)   // 64 mtiles * 3 mats * 3 ntiles
    qkv_impl<192, 16, 12, 3, 3, 12>(bid, x, q0w, q0b, k0w, k0b, v0w, v0b,
                                    ws + Q0_OFF, hws + 2 * (size_t)K0H_OFF,
                                    hws + 2 * (size_t)V0T_OFF, cmap0, smem);
  else             // 64 * 3 * 2 = 384
    qkv_impl<66, 11, 6, 2, 2, 8>(bid - 576, y, q1w, q1b, k1w, k1b, v1w, v1b,
                                 ws + Q1_OFF, hws + 2 * (size_t)K1H_OFF,
                                 hws + 2 * (size_t)V1T_OFF, cmap1, smem);
}

// ---------------------------------------------------------------------------
// Attention v11 — S^T trick on mfma_f32_16x16x16f16 over compacted keys.
// Block = (bh, 64-row q-strip), 4 waves x 1 q-tile of 16 rows.
// ---------------------------------------------------------------------------
template <int H, int DPH, int SKP>
__device__ void attn_impl(int bid, const float* __restrict__ qg,
                          const _Float16* __restrict__ kh,
                          const _Float16* __restrict__ vth,
                          const int* __restrict__ cnts,
                          float* __restrict__ ctx, char* smem)
{
  constexpr int CH = 128;              // keys per chunk
  constexpr int KBUF = CH * SKP + 32;  // +32: kf reads reach key*SKP+15
  constexpr int VST = 136;             // V^T row stride (halves)

  _Float16* sK = (_Float16*)smem;                 // 2 x KBUF
  _Float16* sVT = sK + 2 * KBUF;                  // 2 x DPH*VST

  const int bh = bid >> 4;             // 16 strips per bh
  const int b = bh / H;
  const int h = bh % H;
  const int tid = threadIdx.x;

  const float* qb_ = qg + (size_t)bh * SLEN * DPH;
  const _Float16* kb_ = kh + (size_t)bh * SLEN * SKP;
  const _Float16* vb_ = vth + ((size_t)bh * DPH << 10);
  const int cnt = cnts[b];
  const int nch = (cnt + CH - 1) >> 7;   // dynamic chunk count (1..8)

  // zero the 32-half tails of both sK buffers (never rewritten by commit)
  if (tid < 64) sK[(tid >> 5) * KBUF + CH * SKP + (tid & 31)] = (_Float16)0.f;

  const int wave = tid >> 6, lane = tid & 63;
  const int col = lane & 15, grp = lane >> 4;
  const int qtile = (bid & 15) * 4 + wave;   // 16-row q-tile index

  // Q fragment, B-operand layout: B[k=d=grp*4+j][n=qrow=col], zero-padded
  f16x4 aq;
  {
    const int qrow = qtile * 16 + col;
#pragma unroll
    for (int j = 0; j < 4; ++j) {
      const int d = grp * 4 + j;
      aq[j] = (d < DPH) ? (_Float16)qb_[(size_t)qrow * DPH + d] : (_Float16)0.f;
    }
  }

  // register-staged prefetch / LDS commit
  constexpr int kN = CH * SKP / 8;     // uint4 count for K
  constexpr int vN = DPH * 16;         // uint4 count for V
  const int vd = tid >> 4, vq = tid & 15;
  uint4 pk, pv;
  auto prefetch = [&](int cc) {
    if (tid < kN) pk = ((const uint4*)(kb_ + (size_t)cc * CH * SKP))[tid];
    if (tid < vN) pv = ((const uint4*)(vb_ + ((size_t)vd << 10) + cc * CH))[vq];
  };
  auto commit = [&](int pb) {
    if (tid < kN) ((uint4*)(sK + pb * KBUF))[tid] = pk;
    if (tid < vN) *(uint4*)(sVT + (pb * DPH + vd) * VST + vq * 8) = pv;
  };

  prefetch(0);
  commit(0);
  __syncthreads();

  f32x4 Oacc[2] = {{0.f,0.f,0.f,0.f},{0.f,0.f,0.f,0.f}};
  float lsum = 0.f;
  const int de = (col < DPH) ? col : 0;   // clamped: cols >= DPH discarded

#pragma unroll 1
  for (int c = 0; c < nch; ++c) {
    const int p = c & 1;
    if (c + 1 < nch) prefetch(c + 1);

    const _Float16* sKp = sK + p * KBUF;
    const _Float16* sVp = sVT + p * DPH * VST;
    const int keyr = c * CH + grp * 4;   // this lane's reg-dim key base

#pragma unroll
    for (int kt = 0; kt < CH / 16; ++kt) {
      const f16x4 kf = *(const f16x4*)(sKp + (kt * 16 + col) * SKP + grp * 4);
      const int k0 = keyr + kt * 16;
      const f32x4 biasv = {(k0 < cnt) ? 0.f : -100.f,
                           (k0 + 1 < cnt) ? 0.f : -100.f,
                           (k0 + 2 < cnt) ? 0.f : -100.f,
                           (k0 + 3 < cnt) ? 0.f : -100.f};
      const f32x4 S = __builtin_amdgcn_mfma_f32_16x16x16f16(kf, aq, biasv,
                                                            0, 0, 0);
      const float e0 = EXP2(S[0]), e1 = EXP2(S[1]);
      const float e2 = EXP2(S[2]), e3 = EXP2(S[3]);
      lsum += (e0 + e1) + (e2 + e3);
      const f16x4 pf = {(_Float16)e0, (_Float16)e1, (_Float16)e2, (_Float16)e3};
      const f16x4 vf = *(const f16x4*)(sVp + de * VST + kt * 16 + grp * 4);
      Oacc[kt & 1] = __builtin_amdgcn_mfma_f32_16x16x16f16(pf, vf, Oacc[kt & 1],
                                                           0, 0, 0);
    }

    if (c + 1 < nch) commit(p ^ 1);
    __syncthreads();
  }

  // epilogue — ALL cross-lane ops unconditional (r5's NaN was divergence here)
  f32x4 Osum;
#pragma unroll
  for (int r = 0; r < 4; ++r) Osum[r] = Oacc[0][r] + Oacc[1][r];
  float lred = lsum;
  lred += __shfl_xor(lred, 16);
  lred += __shfl_xor(lred, 32);            // lred = l(qrow=col), all lanes
  float lq[4];
#pragma unroll
  for (int r = 0; r < 4; ++r) lq[r] = __shfl(lred, grp * 4 + r);
  if (col < DPH) {
    const int qrow0 = qtile * 16;
#pragma unroll
    for (int r = 0; r < 4; ++r) {
      const int row = qrow0 + grp * 4 + r;
      ctx[(size_t)(b * SLEN + row) * (H * DPH) + h * DPH + col] = Osum[r] / lq[r];
    }
  }
}

__global__ __launch_bounds__(256) void attn_kernel(float* __restrict__ ws)
{
  extern __shared__ char smem[];
  _Float16* hws = (_Float16*)ws;
  const int* cnts = (const int*)(ws + CNT_OFF);
  const int bid = blockIdx.x;
  if (bid < 1024)  // 64 bh * 16 q-strips
    attn_impl<16, 12, 12>(bid, ws + Q0_OFF, hws + 2 * (size_t)K0H_OFF,
                          hws + 2 * (size_t)V0T_OFF, cnts, ws + C0_OFF, smem);
  else             // 44 bh * 16 = 704
    attn_impl<11, 6, 8>(bid - 1024, ws + Q1_OFF, hws + 2 * (size_t)K1H_OFF,
                        hws + 2 * (size_t)V1T_OFF, cnts + 4, ws + C1_OFF, smem);
}

// ---------------------------------------------------------------------------
// Output projection (f16 MFMA, 3-term hi/lo split => ~fp32 accuracy).
// ---------------------------------------------------------------------------
template <int DIM, int NCH>
__device__ void oproj_impl(int bid, const float* __restrict__ Cx,
                           const float* __restrict__ ow, const float* __restrict__ ob,
                           float* __restrict__ out, char* smem)
{
  const int mt64 = bid & 63;
  const int nt = bid >> 6;
  const int row0 = mt64 * 64, col0 = nt * 64;

  _Float16* sAh = (_Float16*)smem;
  _Float16* sAl = sAh + 64 * 72;
  _Float16* sWTh = sAl + 64 * 72;
  _Float16* sWTl = sWTh + 64 * 72;

  const int tid = threadIdx.x;
  const int wv = tid >> 6, lane = tid & 63;
  f32x4 acc[4] = {{0.f,0.f,0.f,0.f},{0.f,0.f,0.f,0.f},{0.f,0.f,0.f,0.f},{0.f,0.f,0.f,0.f}};

  for (int c = 0; c < NCH; ++c) {
    __syncthreads();
    stage_chunk_split<DIM>(Cx, row0, c * 64, ow, col0, sAh, sAl, sWTh, sWTl, tid);
    __syncthreads();
    mfma_chunk_split(sAh, sAl, sWTh, sWTl, wv, lane, acc);
  }

  const int col = lane & 15, grp = lane >> 4;
  const int cidx = col0 + wv * 16 + col;
  if (cidx < DIM) {
    const float bias = ob[cidx];
#pragma unroll
    for (int mt = 0; mt < 4; ++mt) {
#pragma unroll
      for (int r = 0; r < 4; ++r) {
        const int m = row0 + mt * 16 + grp * 4 + r;
        out[(size_t)m * DIM + cidx] = acc[mt][r] + bias;
      }
    }
  }
}

__global__ __launch_bounds__(256) void oproj_kernel(
    const float* __restrict__ o0w, const float* __restrict__ o0b,
    const float* __restrict__ o1w, const float* __restrict__ o1b,
    float* __restrict__ ws, float* __restrict__ out)
{
  extern __shared__ char smem[];
  const int bid = blockIdx.x;
  if (bid < 192)
    oproj_impl<192, 3>(bid, ws + C0_OFF, o0w, o0b, out, smem);
  else
    oproj_impl<66, 2>(bid - 192, ws + C1_OFF, o1w, o1b, out + OUT0_SIZE, smem);
}

// ---------------------------------------------------------------------------
// Round 12: fused persistent cooperative kernel — all 4 phases, 3 grid syncs.
// ---------------------------------------------------------------------------
struct FusedParams {
  const float *x, *y;
  const int *mask0, *mask1;
  const float *q0w, *q0b, *k0w, *k0b, *v0w, *v0b, *o0w, *o0b;
  const float *q1w, *q1b, *k1w, *k1b, *v1w, *v1b, *o1w, *o1b;
  float* ws;
  float* out;
};

__global__ __launch_bounds__(256, 4) void fused_kernel(FusedParams p)
{
  extern __shared__ char smem[];
  float* ws = p.ws;
  _Float16* hws = (_Float16*)ws;
  const int bid = blockIdx.x;
  const int G = gridDim.x;
  cg::grid_group grid = cg::this_grid();

  int* cmap0 = (int*)(ws + CMAP0_OFF);
  int* cmap1 = (int*)(ws + CMAP1_OFF);
  int* cnts = (int*)(ws + CNT_OFF);

  // ---- phase 0: compaction (8 items) ----
  for (int it = bid; it < 8; it += G)
    compact_phase(it, p.mask0, p.mask1, cmap0, cmap1, cnts,
                  (int*)smem, (int*)smem + 256);
  grid.sync();

  // ---- phase 1: QKV projections (960 items) ----
  for (int it = bid; it < 960; it += G) {
    if (it < 576)
      qkv_impl<192, 16, 12, 3, 3, 12>(it, p.x, p.q0w, p.q0b, p.k0w, p.k0b,
                                      p.v0w, p.v0b, ws + Q0_OFF,
                                      hws + 2 * (size_t)K0H_OFF,
                                      hws + 2 * (size_t)V0T_OFF, cmap0, smem);
    else
      qkv_impl<66, 11, 6, 2, 2, 8>(it - 576, p.y, p.q1w, p.q1b, p.k1w, p.k1b,
                                   p.v1w, p.v1b, ws + Q1_OFF,
                                   hws + 2 * (size_t)K1H_OFF,
                                   hws + 2 * (size_t)V1T_OFF, cmap1, smem);
  }
  grid.sync();

  // ---- phase 2: attention (1728 items) ----
  for (int it = bid; it < 1728; it += G) {
    if (it < 1024)
      attn_impl<16, 12, 12>(it, ws + Q0_OFF, hws + 2 * (size_t)K0H_OFF,
                            hws + 2 * (size_t)V0T_OFF, cnts, ws + C0_OFF, smem);
    else
      attn_impl<11, 6, 8>(it - 1024, ws + Q1_OFF, hws + 2 * (size_t)K1H_OFF,
                          hws + 2 * (size_t)V1T_OFF, cnts + 4, ws + C1_OFF, smem);
  }
  grid.sync();

  // ---- phase 3: output projection (320 items) ----
  for (int it = bid; it < 320; it += G) {
    if (it < 192)
      oproj_impl<192, 3>(it, ws + C0_OFF, p.o0w, p.o0b, p.out, smem);
    else
      oproj_impl<66, 2>(it - 192, ws + C1_OFF, p.o1w, p.o1b, p.out + OUT0_SIZE,
                        smem);
  }
}

// ---------------------------------------------------------------------------
extern "C" void kernel_launch(void* const* d_in, const int* in_sizes, int n_in,
                              void* d_out, int out_size, void* d_ws, size_t ws_size,
                              hipStream_t stream)
{
  const float* x = (const float*)d_in[0];
  const float* y = (const float*)d_in[1];
  const int* mask0 = (const int*)d_in[2];
  const int* mask1 = (const int*)d_in[3];
  const float* q0w = (const float*)d_in[4];  const float* q0b = (const float*)d_in[5];
  const float* k0w = (const float*)d_in[6];  const float* k0b = (const float*)d_in[7];
  const float* v0w = (const float*)d_in[8];  const float* v0b = (const float*)d_in[9];
  const float* o0w = (const float*)d_in[10]; const float* o0b = (const float*)d_in[11];
  const float* q1w = (const float*)d_in[12]; const float* q1b = (const float*)d_in[13];
  const float* k1w = (const float*)d_in[14]; const float* k1b = (const float*)d_in[15];
  const float* v1w = (const float*)d_in[16]; const float* v1b = (const float*)d_in[17];
  const float* o1w = (const float*)d_in[18]; const float* o1b = (const float*)d_in[19];

  float* ws = (float*)d_ws;
  float* out = (float*)d_out;

  // ---- preferred path: one persistent cooperative kernel ----
  FusedParams p = {x, y, mask0, mask1,
                   q0w, q0b, k0w, k0b, v0w, v0b, o0w, o0b,
                   q1w, q1b, k1w, k1b, v1w, v1b, o1w, o1b,
                   ws, out};
  int nb = 0;
  hipError_t occ = hipOccupancyMaxActiveBlocksPerMultiprocessor(
      &nb, fused_kernel, 256, (size_t)FUSED_SMEM);
  if (occ == hipSuccess && nb >= 1) {
    int grid = nb * 256;               // 256 CUs on MI355X
    if (grid > 1728) grid = 1728;      // no phase has more items
    void* args[] = {(void*)&p};
    hipError_t e = hipLaunchCooperativeKernel(fused_kernel, dim3(grid),
                                              dim3(256), args,
                                              (unsigned)FUSED_SMEM, stream);
    if (e == hipSuccess) return;
  }

  // ---- fallback: proven r11 4-kernel path ----
  const int qkv_smem = 2 * 64 * 72 * 2;    // 18432 B
  const int oproj_smem = 4 * 64 * 72 * 2;  // 36864 B
  const int attn_smem = 2 * (128 * 12 + 32) * 2 + 2 * 12 * 136 * 2;

  compact_kernel<<<8, 256, 0, stream>>>(mask0, mask1,
                                        (int*)(ws + CMAP0_OFF),
                                        (int*)(ws + CMAP1_OFF),
                                        (int*)(ws + CNT_OFF));
  qkv_kernel<<<960, 256, qkv_smem, stream>>>(x, y, q0w, q0b, k0w, k0b, v0w, v0b,
                                             q1w, q1b, k1w, k1b, v1w, v1b, ws);
  attn_kernel<<<1728, 256, attn_smem, stream>>>(ws);
  oproj_kernel<<<320, 256, oproj_smem, stream>>>(o0w, o0b, o1w, o1b, ws, out);
}

// Round 2
// 144.449 us; speedup vs baseline: 2.1818x; 2.1818x over previous
//
#include <hip/hip_runtime.h>
#include <math.h>

// Model_7310034338114: two Flaubert/XLM MHA blocks (eval), fp32 in/out.
// inst0: x (4,1024,192), 16 heads, dph=12. inst1: y (4,1024,66), 11 heads, dph=6.
//
// Round 13: back to multi-kernel (r12's cooperative fusion was 2x WORSE:
// grid.sync on 8 non-coherent XCD L2s is a ~100us-class barrier, and the
// fused kernel dragged oproj's 36.9KB LDS through every phase -> 4 blocks/CU.
// Kernel boundaries are the CHEAP grid barrier on CDNA4).
// Changes vs the 156us r11 baseline:
//   1. compact kernel folded into qkv as a per-block in-LDS mask scan
//      (K/V blocks only; runs under chunk-0 load latency) -> 3 kernels.
//   2. qkv/oproj staging converted to register-prefetch (attn already had
//      it): global->reg issued before the previous chunk's MFMA, reg->LDS
//      commit after the barrier -> cold-HBM latency overlapped instead of
//      exposed once per chunk (oproj is 1.25 blocks/CU; no TLP to hide it).
//   3. attn kernel byte-identical to r11.

#define BS 4
#define SLEN 1024

// workspace float offsets
#define Q0_OFF 0              // f32 [4][16][1024][12]  (786432)
#define C0_OFF 786432         // f32 [4096][192]        (786432)
#define Q1_OFF 1572864        // f32 [4][11][1024][6]   (270336)
#define C1_OFF 1843200        // f32 [4096][66]         (270336)
#define K0H_OFF 2113536       // f16 [4][16][1024][12]  (786432 h = 393216 fl)
#define V0T_OFF 2506752       // f16 [4][16][12][1024]  (786432 h)
#define K1H_OFF 2899968       // f16 [4][11][1024][8]   (360448 h = 180224 fl)
#define V1T_OFF 3080192       // f16 [4][11][6][1024]   (270336 h = 135168 fl)
#define CNT_OFF 3223552       // int [8] (inst*4 + b)

#define OUT0_SIZE 786432      // 4096*192

#if __has_builtin(__builtin_amdgcn_exp2f)
#define EXP2(x) __builtin_amdgcn_exp2f(x)
#else
#define EXP2(x) __expf((x) * 0.69314718056f)
#endif

typedef _Float16 f16x2 __attribute__((ext_vector_type(2)));
typedef _Float16 f16x4 __attribute__((ext_vector_type(4)));
typedef _Float16 f16x8 __attribute__((ext_vector_type(8)));
typedef float f32x4 __attribute__((ext_vector_type(4)));

// ---------------------------------------------------------------------------
// f16-MFMA GEMM building blocks (round-4 proven): BM=BN=BK=64, 4 waves.
// ---------------------------------------------------------------------------
__device__ __forceinline__ void mfma_chunk(const _Float16* sA, const _Float16* sWT,
                                           int wv, int lane, f32x4 acc[4])
{
  const int col = lane & 15, grp = lane >> 4;
#pragma unroll
  for (int ks = 0; ks < 2; ++ks) {
    const f16x8 bf = *(const f16x8*)(sWT + (wv * 16 + col) * 72 + ks * 32 + grp * 8);
#pragma unroll
    for (int mt = 0; mt < 4; ++mt) {
      const f16x8 af = *(const f16x8*)(sA + (mt * 16 + col) * 72 + ks * 32 + grp * 8);
      acc[mt] = __builtin_amdgcn_mfma_f32_16x16x32_f16(af, bf, acc[mt], 0, 0, 0);
    }
  }
}

__device__ __forceinline__ void mfma_chunk_split(
    const _Float16* sAh, const _Float16* sAl,
    const _Float16* sWTh, const _Float16* sWTl,
    int wv, int lane, f32x4 acc[4])
{
  const int col = lane & 15, grp = lane >> 4;
#pragma unroll
  for (int ks = 0; ks < 2; ++ks) {
    const int boff = (wv * 16 + col) * 72 + ks * 32 + grp * 8;
    const f16x8 bh = *(const f16x8*)(sWTh + boff);
    const f16x8 bl = *(const f16x8*)(sWTl + boff);
#pragma unroll
    for (int mt = 0; mt < 4; ++mt) {
      const int aoff = (mt * 16 + col) * 72 + ks * 32 + grp * 8;
      const f16x8 ah = *(const f16x8*)(sAh + aoff);
      const f16x8 al = *(const f16x8*)(sAl + aoff);
      acc[mt] = __builtin_amdgcn_mfma_f32_16x16x32_f16(ah, bh, acc[mt], 0, 0, 0);
      acc[mt] = __builtin_amdgcn_mfma_f32_16x16x32_f16(ah, bl, acc[mt], 0, 0, 0);
      acc[mt] = __builtin_amdgcn_mfma_f32_16x16x32_f16(al, bh, acc[mt], 0, 0, 0);
    }
  }
}

// ---------------------------------------------------------------------------
// QKV projection + integrated mask scan.
// Q -> f32 [b][h][s][dph] scaled log2(e)/sqrt(dph);
// K -> f16 [b][h][slot(s)][KST]; V -> f16 transposed [b][h][d][slot(s)].
// K/V blocks compute their own 64 compaction slots in-block (sSP), and the
// (mat==1, nt==0, first row tile of b) block publishes cnts[b] for attn.
// ---------------------------------------------------------------------------
template <int DIM, int H, int DPH, int NT, int NCH, int KST>
__device__ void qkv_impl(int bid, const float* __restrict__ X,
                         const int* __restrict__ mask,
                         const float* __restrict__ qw, const float* __restrict__ qb,
                         const float* __restrict__ kw, const float* __restrict__ kb,
                         const float* __restrict__ vw, const float* __restrict__ vb,
                         float* __restrict__ qo, _Float16* __restrict__ kh,
                         _Float16* __restrict__ vth, int* __restrict__ cnt_out,
                         char* smem)
{
  const int mt64 = bid & 63;
  const int rest = bid >> 6;
  const int mat = rest / NT;
  const int nt = rest % NT;
  const int row0 = mt64 * 64, col0 = nt * 64;

  const float* W = (mat == 0) ? qw : (mat == 1) ? kw : vw;
  const float* B = (mat == 0) ? qb : (mat == 1) ? kb : vb;
  const float scale = (mat == 0) ? (1.44269504089f / sqrtf((float)DPH)) : 1.0f;

  _Float16* sA = (_Float16*)smem;            // 64*72 halves
  _Float16* sWT = sA + 64 * 72;              // 64*72 halves
  int* sSP = (int*)(smem + 2 * 64 * 72 * 2); // 64 ints, persists to epilogue

  const int tid = threadIdx.x;
  const int wv = tid >> 6, lane = tid & 63;

  // register-staged prefetch (global->reg) / commit (reg->LDS as f16)
  float2 rA[8], rW[8];
  auto qprefetch = [&](int c) {
    const int kc = c * 64;
#pragma unroll
    for (int t = 0; t < 8; ++t) {
      const int idx = tid + t * 256;
      {
        const int m = idx >> 5, k = (idx & 31) * 2;
        rA[t] = (kc + k < DIM)
                    ? *(const float2*)(X + (size_t)(row0 + m) * DIM + kc + k)
                    : make_float2(0.f, 0.f);
      }
      {
        const int k = idx >> 5, n = (idx & 31) * 2;
        rW[t] = (kc + k < DIM && col0 + n < DIM)
                    ? *(const float2*)(W + (size_t)(kc + k) * DIM + col0 + n)
                    : make_float2(0.f, 0.f);
      }
    }
  };
  auto qcommit = [&]() {
#pragma unroll
    for (int t = 0; t < 8; ++t) {
      const int idx = tid + t * 256;
      {
        const int m = idx >> 5, k = (idx & 31) * 2;
        *(f16x2*)(sA + m * 72 + k) = (f16x2){(_Float16)rA[t].x, (_Float16)rA[t].y};
      }
      {
        const int k = idx >> 5, n = (idx & 31) * 2;
        sWT[n * 72 + k] = (_Float16)rW[t].x;
        sWT[(n + 1) * 72 + k] = (_Float16)rW[t].y;
      }
    }
  };

  qprefetch(0);   // issue chunk-0 loads first; scan below runs under their latency

  // ---- in-block mask scan (K/V blocks only): sSP[j] = slot of row row0+j ----
  if (mat != 0) {
    int* sS = (int*)smem;          // aliases sA: used strictly before staging
    const int b = row0 >> 10;
    const int* m = mask + (b << 10);
    int mv[4], s4 = 0;
#pragma unroll
    for (int i = 0; i < 4; ++i) { mv[i] = m[tid * 4 + i] ? 1 : 0; s4 += mv[i]; }
    sS[tid] = s4;
    __syncthreads();
    for (int off = 1; off < 256; off <<= 1) {   // Hillis-Steele inclusive scan
      const int v = sS[tid];
      const int add = (tid >= off) ? sS[tid - off] : 0;
      __syncthreads();
      sS[tid] = v + add;
      __syncthreads();
    }
    const int tot = sS[255];
    int u = tid ? sS[tid - 1] : 0;   // unmasked count before this thread's span
    const int s0 = row0 & 1023;
#pragma unroll
    for (int i = 0; i < 4; ++i) {
      const int s = tid * 4 + i;
      const int sp = mv[i] ? u : tot + (s - u);
      u += mv[i];
      const unsigned rel = (unsigned)(s - s0);
      if (rel < 64u) sSP[rel] = sp;
    }
    if (mat == 1 && nt == 0 && s0 == 0 && tid == 0) cnt_out[b] = tot;
    __syncthreads();   // sSP visible; sS region free for staging
  }

  f32x4 acc[4] = {{0.f,0.f,0.f,0.f},{0.f,0.f,0.f,0.f},{0.f,0.f,0.f,0.f},{0.f,0.f,0.f,0.f}};

  for (int c = 0; c < NCH; ++c) {
    __syncthreads();                 // previous mfma done reading LDS
    qcommit();
    __syncthreads();
    if (c + 1 < NCH) qprefetch(c + 1);   // loads overlap this chunk's MFMA
    mfma_chunk(sA, sWT, wv, lane, acc);
  }

  const int col = lane & 15, grp = lane >> 4;
  const int cidx = col0 + wv * 16 + col;
  if (cidx < DIM) {
    const float bias = B[cidx];
    const int h = cidx / DPH, d = cidx % DPH;
#pragma unroll
    for (int mt = 0; mt < 4; ++mt) {
#pragma unroll
      for (int r = 0; r < 4; ++r) {
        const int m = row0 + mt * 16 + grp * 4 + r;
        const int b = m >> 10, s = m & 1023;
        const float v = acc[mt][r] + bias;
        const int bh = b * H + h;
        if (mat == 0) {
          qo[(size_t)((bh << 10) + s) * DPH + d] = v * scale;
        } else {
          const int sp = sSP[mt * 16 + grp * 4 + r];
          if (mat == 1)
            kh[(size_t)((bh << 10) + sp) * KST + d] = (_Float16)v;
          else
            vth[((size_t)(bh * DPH + d) << 10) + sp] = (_Float16)v;
        }
      }
    }
  }
}

__global__ __launch_bounds__(256) void qkv_kernel(
    const float* __restrict__ x, const float* __restrict__ y,
    const int* __restrict__ mask0, const int* __restrict__ mask1,
    const float* __restrict__ q0w, const float* __restrict__ q0b,
    const float* __restrict__ k0w, const float* __restrict__ k0b,
    const float* __restrict__ v0w, const float* __restrict__ v0b,
    const float* __restrict__ q1w, const float* __restrict__ q1b,
    const float* __restrict__ k1w, const float* __restrict__ k1b,
    const float* __restrict__ v1w, const float* __restrict__ v1b,
    float* __restrict__ ws)
{
  extern __shared__ char smem[];
  _Float16* hws = (_Float16*)ws;
  int* cnts = (int*)(ws + CNT_OFF);
  const int bid = blockIdx.x;
  if (bid < 576)   // 64 mtiles * 3 mats * 3 ntiles
    qkv_impl<192, 16, 12, 3, 3, 12>(bid, x, mask0, q0w, q0b, k0w, k0b, v0w, v0b,
                                    ws + Q0_OFF, hws + 2 * (size_t)K0H_OFF,
                                    hws + 2 * (size_t)V0T_OFF, cnts, smem);
  else             // 64 * 3 * 2 = 384
    qkv_impl<66, 11, 6, 2, 2, 8>(bid - 576, y, mask1, q1w, q1b, k1w, k1b, v1w, v1b,
                                 ws + Q1_OFF, hws + 2 * (size_t)K1H_OFF,
                                 hws + 2 * (size_t)V1T_OFF, cnts + 4, smem);
}

// ---------------------------------------------------------------------------
// Attention v11 (unchanged, proven) — S^T trick on mfma_f32_16x16x16f16 over
// compacted keys. Block = (bh, 64-row q-strip), 4 waves x 1 q-tile of 16 rows.
// ---------------------------------------------------------------------------
template <int H, int DPH, int SKP>
__device__ void attn_impl(int bid, const float* __restrict__ qg,
                          const _Float16* __restrict__ kh,
                          const _Float16* __restrict__ vth,
                          const int* __restrict__ cnts,
                          float* __restrict__ ctx, char* smem)
{
  constexpr int CH = 128;              // keys per chunk
  constexpr int KBUF = CH * SKP + 32;  // +32: kf reads reach key*SKP+15
  constexpr int VST = 136;             // V^T row stride (halves)

  _Float16* sK = (_Float16*)smem;                 // 2 x KBUF
  _Float16* sVT = sK + 2 * KBUF;                  // 2 x DPH*VST

  const int bh = bid >> 4;             // 16 strips per bh
  const int b = bh / H;
  const int h = bh % H;
  const int tid = threadIdx.x;

  const float* qb_ = qg + (size_t)bh * SLEN * DPH;
  const _Float16* kb_ = kh + (size_t)bh * SLEN * SKP;
  const _Float16* vb_ = vth + ((size_t)bh * DPH << 10);
  const int cnt = cnts[b];
  const int nch = (cnt + CH - 1) >> 7;   // dynamic chunk count (1..8)

  // zero the 32-half tails of both sK buffers (never rewritten by commit)
  if (tid < 64) sK[(tid >> 5) * KBUF + CH * SKP + (tid & 31)] = (_Float16)0.f;

  const int wave = tid >> 6, lane = tid & 63;
  const int col = lane & 15, grp = lane >> 4;
  const int qtile = (bid & 15) * 4 + wave;   // 16-row q-tile index

  // Q fragment, B-operand layout: B[k=d=grp*4+j][n=qrow=col], zero-padded
  f16x4 aq;
  {
    const int qrow = qtile * 16 + col;
#pragma unroll
    for (int j = 0; j < 4; ++j) {
      const int d = grp * 4 + j;
      aq[j] = (d < DPH) ? (_Float16)qb_[(size_t)qrow * DPH + d] : (_Float16)0.f;
    }
  }

  // register-staged prefetch / LDS commit
  constexpr int kN = CH * SKP / 8;     // uint4 count for K
  constexpr int vN = DPH * 16;         // uint4 count for V
  const int vd = tid >> 4, vq = tid & 15;
  uint4 pk, pv;
  auto prefetch = [&](int cc) {
    if (tid < kN) pk = ((const uint4*)(kb_ + (size_t)cc * CH * SKP))[tid];
    if (tid < vN) pv = ((const uint4*)(vb_ + ((size_t)vd << 10) + cc * CH))[vq];
  };
  auto commit = [&](int pb) {
    if (tid < kN) ((uint4*)(sK + pb * KBUF))[tid] = pk;
    if (tid < vN) *(uint4*)(sVT + (pb * DPH + vd) * VST + vq * 8) = pv;
  };

  prefetch(0);
  commit(0);
  __syncthreads();

  f32x4 Oacc[2] = {{0.f,0.f,0.f,0.f},{0.f,0.f,0.f,0.f}};
  float lsum = 0.f;
  const int de = (col < DPH) ? col : 0;   // clamped: cols >= DPH discarded

#pragma unroll 1
  for (int c = 0; c < nch; ++c) {
    const int p = c & 1;
    if (c + 1 < nch) prefetch(c + 1);

    const _Float16* sKp = sK + p * KBUF;
    const _Float16* sVp = sVT + p * DPH * VST;
    const int keyr = c * CH + grp * 4;   // this lane's reg-dim key base

#pragma unroll
    for (int kt = 0; kt < CH / 16; ++kt) {
      const f16x4 kf = *(const f16x4*)(sKp + (kt * 16 + col) * SKP + grp * 4);
      const int k0 = keyr + kt * 16;
      const f32x4 biasv = {(k0 < cnt) ? 0.f : -100.f,
                           (k0 + 1 < cnt) ? 0.f : -100.f,
                           (k0 + 2 < cnt) ? 0.f : -100.f,
                           (k0 + 3 < cnt) ? 0.f : -100.f};
      const f32x4 S = __builtin_amdgcn_mfma_f32_16x16x16f16(kf, aq, biasv,
                                                            0, 0, 0);
      const float e0 = EXP2(S[0]), e1 = EXP2(S[1]);
      const float e2 = EXP2(S[2]), e3 = EXP2(S[3]);
      lsum += (e0 + e1) + (e2 + e3);
      const f16x4 pf = {(_Float16)e0, (_Float16)e1, (_Float16)e2, (_Float16)e3};
      const f16x4 vf = *(const f16x4*)(sVp + de * VST + kt * 16 + grp * 4);
      Oacc[kt & 1] = __builtin_amdgcn_mfma_f32_16x16x16f16(pf, vf, Oacc[kt & 1],
                                                           0, 0, 0);
    }

    if (c + 1 < nch) commit(p ^ 1);
    __syncthreads();
  }

  // epilogue — ALL cross-lane ops unconditional (r5's NaN was divergence here)
  f32x4 Osum;
#pragma unroll
  for (int r = 0; r < 4; ++r) Osum[r] = Oacc[0][r] + Oacc[1][r];
  float lred = lsum;
  lred += __shfl_xor(lred, 16);
  lred += __shfl_xor(lred, 32);            // lred = l(qrow=col), all lanes
  float lq[4];
#pragma unroll
  for (int r = 0; r < 4; ++r) lq[r] = __shfl(lred, grp * 4 + r);
  if (col < DPH) {
    const int qrow0 = qtile * 16;
#pragma unroll
    for (int r = 0; r < 4; ++r) {
      const int row = qrow0 + grp * 4 + r;
      ctx[(size_t)(b * SLEN + row) * (H * DPH) + h * DPH + col] = Osum[r] / lq[r];
    }
  }
}

__global__ __launch_bounds__(256) void attn_kernel(float* __restrict__ ws)
{
  extern __shared__ char smem[];
  _Float16* hws = (_Float16*)ws;
  const int* cnts = (const int*)(ws + CNT_OFF);
  const int bid = blockIdx.x;
  if (bid < 1024)  // 64 bh * 16 q-strips
    attn_impl<16, 12, 12>(bid, ws + Q0_OFF, hws + 2 * (size_t)K0H_OFF,
                          hws + 2 * (size_t)V0T_OFF, cnts, ws + C0_OFF, smem);
  else             // 44 bh * 16 = 704
    attn_impl<11, 6, 8>(bid - 1024, ws + Q1_OFF, hws + 2 * (size_t)K1H_OFF,
                        hws + 2 * (size_t)V1T_OFF, cnts + 4, ws + C1_OFF, smem);
}

// ---------------------------------------------------------------------------
// Output projection (f16 MFMA, 3-term hi/lo split => ~fp32 accuracy), now with
// register-prefetch staging (1.25 blocks/CU here: latency must be hidden by
// ILP, there is no TLP).
// ---------------------------------------------------------------------------
template <int DIM, int NCH>
__device__ void oproj_impl(int bid, const float* __restrict__ Cx,
                           const float* __restrict__ ow, const float* __restrict__ ob,
                           float* __restrict__ out, char* smem)
{
  const int mt64 = bid & 63;
  const int nt = bid >> 6;
  const int row0 = mt64 * 64, col0 = nt * 64;

  _Float16* sAh = (_Float16*)smem;
  _Float16* sAl = sAh + 64 * 72;
  _Float16* sWTh = sAl + 64 * 72;
  _Float16* sWTl = sWTh + 64 * 72;

  const int tid = threadIdx.x;
  const int wv = tid >> 6, lane = tid & 63;

  float2 rA[8], rW[8];
  auto oprefetch = [&](int c) {
    const int kc = c * 64;
#pragma unroll
    for (int t = 0; t < 8; ++t) {
      const int idx = tid + t * 256;
      {
        const int m = idx >> 5, k = (idx & 31) * 2;
        rA[t] = (kc + k < DIM)
                    ? *(const float2*)(Cx + (size_t)(row0 + m) * DIM + kc + k)
                    : make_float2(0.f, 0.f);
      }
      {
        const int k = idx >> 5, n = (idx & 31) * 2;
        rW[t] = (kc + k < DIM && col0 + n < DIM)
                    ? *(const float2*)(ow + (size_t)(kc + k) * DIM + col0 + n)
                    : make_float2(0.f, 0.f);
      }
    }
  };
  auto ocommit = [&]() {
#pragma unroll
    for (int t = 0; t < 8; ++t) {
      const int idx = tid + t * 256;
      {
        const int m = idx >> 5, k = (idx & 31) * 2;
        const _Float16 hx = (_Float16)rA[t].x, hy = (_Float16)rA[t].y;
        *(f16x2*)(sAh + m * 72 + k) = (f16x2){hx, hy};
        *(f16x2*)(sAl + m * 72 + k) =
            (f16x2){(_Float16)(rA[t].x - (float)hx), (_Float16)(rA[t].y - (float)hy)};
      }
      {
        const int k = idx >> 5, n = (idx & 31) * 2;
        const _Float16 hx = (_Float16)rW[t].x, hy = (_Float16)rW[t].y;
        sWTh[n * 72 + k] = hx;
        sWTh[(n + 1) * 72 + k] = hy;
        sWTl[n * 72 + k] = (_Float16)(rW[t].x - (float)hx);
        sWTl[(n + 1) * 72 + k] = (_Float16)(rW[t].y - (float)hy);
      }
    }
  };

  oprefetch(0);

  f32x4 acc[4] = {{0.f,0.f,0.f,0.f},{0.f,0.f,0.f,0.f},{0.f,0.f,0.f,0.f},{0.f,0.f,0.f,0.f}};

  for (int c = 0; c < NCH; ++c) {
    __syncthreads();
    ocommit();
    __syncthreads();
    if (c + 1 < NCH) oprefetch(c + 1);
    mfma_chunk_split(sAh, sAl, sWTh, sWTl, wv, lane, acc);
  }

  const int col = lane & 15, grp = lane >> 4;
  const int cidx = col0 + wv * 16 + col;
  if (cidx < DIM) {
    const float bias = ob[cidx];
#pragma unroll
    for (int mt = 0; mt < 4; ++mt) {
#pragma unroll
      for (int r = 0; r < 4; ++r) {
        const int m = row0 + mt * 16 + grp * 4 + r;
        out[(size_t)m * DIM + cidx] = acc[mt][r] + bias;
      }
    }
  }
}

__global__ __launch_bounds__(256) void oproj_kernel(
    const float* __restrict__ o0w, const float* __restrict__ o0b,
    const float* __restrict__ o1w, const float* __restrict__ o1b,
    float* __restrict__ ws, float* __restrict__ out)
{
  extern __shared__ char smem[];
  const int bid = blockIdx.x;
  if (bid < 192)
    oproj_impl<192, 3>(bid, ws + C0_OFF, o0w, o0b, out, smem);
  else
    oproj_impl<66, 2>(bid - 192, ws + C1_OFF, o1w, o1b, out + OUT0_SIZE, smem);
}

// ---------------------------------------------------------------------------
extern "C" void kernel_launch(void* const* d_in, const int* in_sizes, int n_in,
                              void* d_out, int out_size, void* d_ws, size_t ws_size,
                              hipStream_t stream)
{
  const float* x = (const float*)d_in[0];
  const float* y = (const float*)d_in[1];
  const int* mask0 = (const int*)d_in[2];
  const int* mask1 = (const int*)d_in[3];
  const float* q0w = (const float*)d_in[4];  const float* q0b = (const float*)d_in[5];
  const float* k0w = (const float*)d_in[6];  const float* k0b = (const float*)d_in[7];
  const float* v0w = (const float*)d_in[8];  const float* v0b = (const float*)d_in[9];
  const float* o0w = (const float*)d_in[10]; const float* o0b = (const float*)d_in[11];
  const float* q1w = (const float*)d_in[12]; const float* q1b = (const float*)d_in[13];
  const float* k1w = (const float*)d_in[14]; const float* k1b = (const float*)d_in[15];
  const float* v1w = (const float*)d_in[16]; const float* v1b = (const float*)d_in[17];
  const float* o1w = (const float*)d_in[18]; const float* o1b = (const float*)d_in[19];

  float* ws = (float*)d_ws;
  float* out = (float*)d_out;

  const int qkv_smem = 2 * 64 * 72 * 2 + 64 * 4;   // 18688 B (staging + sSP)
  const int oproj_smem = 4 * 64 * 72 * 2;          // 36864 B
  // attn: sK 2*(128*12+32)*2 = 6272 + sVT 2*12*136*2 = 6528 -> 12800 B
  const int attn_smem = 2 * (128 * 12 + 32) * 2 + 2 * 12 * 136 * 2;

  qkv_kernel<<<960, 256, qkv_smem, stream>>>(x, y, mask0, mask1,
                                             q0w, q0b, k0w, k0b, v0w, v0b,
                                             q1w, q1b, k1w, k1b, v1w, v1b, ws);
  attn_kernel<<<1728, 256, attn_smem, stream>>>(ws);
  oproj_kernel<<<320, 256, oproj_smem, stream>>>(o0w, o0b, o1w, o1b, ws, out);
}